// Round 2
// baseline (305.777 us; speedup 1.0000x reference)
//
#include <hip/hip_runtime.h>
#include <hip/hip_bf16.h>
#include <math.h>

#define NN 256
#define DD 128
#define EE 64
#define APAD 392   // kernel2 A row stride (ushorts)
#define RPAD 136   // kernel2 rbuf row stride (ushorts)

typedef __attribute__((ext_vector_type(8))) short short8;
typedef __attribute__((ext_vector_type(4))) float f32x4;

static __device__ __forceinline__ unsigned short f2bf(float f) {
    __hip_bfloat16 b = __float2bfloat16(f);
    return *reinterpret_cast<unsigned short*>(&b);
}

static __device__ __forceinline__ float sigm(float l) {
    return __fdividef(1.f, 1.f + __expf(-l));
}

// ---------------- Kernel 1: gate + masked aggregation (+ u1t/u2t pack) -------
// R13 structure: j-ownership decomposition, BARRIER-FREE hot loop.
//   wave w owns j-tiles jt = w, w+4, w+8,... for ALL 128 d.
// Each wave builds A-fragments for its own 16 j-rows in registers (R10's
// verified build) and feeds them to 16 MFMAs (8 d-tiles x 2 K-halves): the
// build is amortized 4x with no duplication (R10's flaw), no LDS P-buffer
// and no per-tile barrier (R12's flaw — 9 barriers/block convoyed; profiled
// pathologically). W2 is staged once to LDS as bf16 fragments, frag-major =
// conflict-free b128 reads; sh_q4 uses slot perm ((e&7)<<3)|(e>>3) so the 4
// quads hit consecutive 16B slots. Waves combine sum/max partials via one
// 4KB LDS buffer + single barrier at the end.
__global__ __launch_bounds__(256, 4)
void ecgc_gate(const float* __restrict__ h_g,
               const float* __restrict__ ef_g,
               const int*   __restrict__ mask_g,
               const float* __restrict__ W1_g,
               const float* __restrict__ b1_g,
               const float* __restrict__ W2_g,
               const float* __restrict__ b2_g,
               const float* __restrict__ U1_g,
               const float* __restrict__ U2_g,
               float*          __restrict__ aggf,
               unsigned short* __restrict__ u1t,
               unsigned short* __restrict__ u2t)
{
    const int bi   = blockIdx.x;
    const int t    = threadIdx.x;
    const int lane = t & 63;
    const int w    = t >> 6;
    const int m16  = lane & 15;
    const int quad = lane >> 4;

    __shared__ __align__(16) float sh_ef4[NN * 4];        // 4 KB
    __shared__ __align__(16) float sh_q4[EE * 4];         // 1 KB, slot-permuted
    __shared__ float sh_basep[4 * EE];                    // 1 KB
    __shared__ float sh_w1e[3 * EE];
    __shared__ int   sh_jlist[NN], sh_wcnt[4], sh_cnt;
    __shared__ __align__(16) unsigned short sh_w2[8192];  // 16 KB frag-major
    __shared__ float sh_rsum[4 * DD], sh_rmax[4 * DD];    // 4 KB

    // ---- u1t/u2t bf16 pack slice: 65536 elems over 2048 blocks ----
    // frag-major [k>>3][d][k&7]: kernel2's B loads are 256-B coalesced runs.
    if (t < 32) {
        const int flat = bi * 32 + t;
        if (flat < 384 * DD) {
            const int d = flat / 384, k = flat - d * 384;
            u1t[((k >> 3) * DD + d) * 8 + (k & 7)] = f2bf(U1_g[k * DD + d]);
        } else {
            const int f2i = flat - 384 * DD;
            const int d = f2i >> 7, k = f2i & 127;
            u2t[((k >> 3) * DD + d) * 8 + (k & 7)] = f2bf(U2_g[k * DD + d]);
        }
    }

    // ---- stage edge feats ----
    {
        const float* efr = ef_g + (size_t)bi * NN * 3;
        sh_ef4[t * 4 + 0] = efr[t * 3 + 0];
        sh_ef4[t * 4 + 1] = efr[t * 3 + 1];
        sh_ef4[t * 4 + 2] = efr[t * 3 + 2];
        sh_ef4[t * 4 + 3] = 0.f;
    }
    if (t < 192) sh_w1e[t] = W1_g[(DD + (t >> 6)) * EE + (t & 63)];

    const int mk = (mask_g[bi * NN + t] != 0) ? 1 : 0;
    const unsigned long long bal = __ballot(mk);
    if (lane == 0) sh_wcnt[w] = __popcll(bal);
    const int pre = __popcll(bal & ((1ull << lane) - 1ull));

    // basep: thread (e = t&63) partial over d-range [w*32, w*32+32)
    {
        const int e = t & 63;
        float acc = 0.f;
        #pragma unroll 8
        for (int d = w * 32; d < w * 32 + 32; ++d)
            acc = fmaf(h_g[bi * DD + d], W1_g[d * EE + e], acc);
        sh_basep[w * EE + e] = acc;
    }

    // ---- stage W2 as bf16 fragments, frag-major:
    // flat = (((dt*2+kh)*4+quad)*16 + m16)*8 + jj  holds W2[kh*32+quad*8+jj][dt*16+m16]
    // Each thread writes 4 contiguous short8 chunks -> conflict-free stores.
    {
        #pragma unroll
        for (int s = 0; s < 4; ++s) {
            const int c   = s * 256 + t;           // chunk 0..1023
            const int cm  = c & 15;                // m16
            const int cq  = (c >> 4) & 3;          // quad
            const int ckh = (c >> 6) & 1;          // kh
            const int cdt = c >> 7;                // dt
            const int k0  = ckh * 32 + cq * 8;
            const int d   = cdt * 16 + cm;
            unsigned short tmp[8];
            #pragma unroll
            for (int jj = 0; jj < 8; ++jj) tmp[jj] = f2bf(W2_g[(k0 + jj) * DD + d]);
            *(short8*)&sh_w2[c * 8] = *(const short8*)tmp;
        }
    }

    // per-dt constants for this lane's d = dt*16+m16
    float nb2[8], flip[8];
    #pragma unroll
    for (int dt = 0; dt < 8; ++dt) {
        const int d = dt * 16 + m16;
        nb2[dt]  = b2_g[d];
        flip[dt] = (h_g[bi * DD + d] >= 0.f) ? 1.f : -1.f;
    }
    __syncthreads();   // barrier 1: wcnt/basep/w1e ready

    {
        int wbase = 0;
        for (int ww = 0; ww < w; ++ww) wbase += sh_wcnt[ww];
        if (mk) sh_jlist[wbase + pre] = t;
        if (t == 0) sh_cnt = sh_wcnt[0] + sh_wcnt[1] + sh_wcnt[2] + sh_wcnt[3];
    }
    if (t < EE) {
        const float base = b1_g[t] + sh_basep[t] + sh_basep[EE + t] +
                           sh_basep[2 * EE + t] + sh_basep[3 * EE + t];
        const int s = ((t & 7) << 3) | (t >> 3);   // slot perm: quads -> consecutive slots
        sh_q4[s * 4 + 0] = base;
        sh_q4[s * 4 + 1] = sh_w1e[t];
        sh_q4[s * 4 + 2] = sh_w1e[EE + t];
        sh_q4[s * 4 + 3] = sh_w1e[2 * EE + t];
    }
    __syncthreads();   // barrier 2: jlist/q4/w2 ready.  Hot loop is barrier-free.

    const int cnt = sh_cnt;
    const int njt = (cnt + 15) >> 4;

    float sum2[8], mm[8];
    #pragma unroll
    for (int dt = 0; dt < 8; ++dt) { sum2[dt] = 0.f; mm[dt] = -3.0e38f; }

    for (int jt = w; jt < njt; jt += 4) {
        const int row = jt * 16 + m16;              // < 256 always
        int jl = sh_jlist[row];
        jl = (row < cnt) ? jl : 0;                  // clamp stale tail values
        const float4 efv = *(const float4*)&sh_ef4[jl * 4];

        // build this wave's A fragments (e 0..31 -> ua, 32..63 -> ub)
        // slot of e=quad*8+jj: ((jj)<<3)|quad ; of e=32+quad*8+jj: (jj<<3)|(4+quad)
        union { short8 s; __hip_bfloat162 h2[4]; } ua, ub;
        #pragma unroll
        for (int p = 0; p < 4; ++p) {
            const f32x4 qa0 = *(const f32x4*)&sh_q4[((2*p    ) * 8 + quad) * 4];
            const f32x4 qa1 = *(const f32x4*)&sh_q4[((2*p + 1) * 8 + quad) * 4];
            const f32x4 qb0 = *(const f32x4*)&sh_q4[((2*p    ) * 8 + 4 + quad) * 4];
            const f32x4 qb1 = *(const f32x4*)&sh_q4[((2*p + 1) * 8 + 4 + quad) * 4];
            float2 va, vb;
            va.x = fmaxf(fmaf(efv.z, qa0[3], fmaf(efv.y, qa0[2], fmaf(efv.x, qa0[1], qa0[0]))), 0.f);
            va.y = fmaxf(fmaf(efv.z, qa1[3], fmaf(efv.y, qa1[2], fmaf(efv.x, qa1[1], qa1[0]))), 0.f);
            vb.x = fmaxf(fmaf(efv.z, qb0[3], fmaf(efv.y, qb0[2], fmaf(efv.x, qb0[1], qb0[0]))), 0.f);
            vb.y = fmaxf(fmaf(efv.z, qb1[3], fmaf(efv.y, qb1[2], fmaf(efv.x, qb1[1], qb1[0]))), 0.f);
            ua.h2[p] = __float22bfloat162_rn(va);
            ub.h2[p] = __float22bfloat162_rn(vb);
        }

        const bool tail = (jt == njt - 1) && (cnt & 15);
        #pragma unroll
        for (int dt = 0; dt < 8; ++dt) {
            const int fb = ((dt * 8 + quad) * 16 + m16) * 8;   // kh=0 fragment
            const short8 b0 = *(const short8*)&sh_w2[fb];
            const short8 b1 = *(const short8*)&sh_w2[fb + 512]; // kh=1: +4*16*8
            f32x4 acc = {nb2[dt], nb2[dt], nb2[dt], nb2[dt]};
            acc = __builtin_amdgcn_mfma_f32_16x16x32_bf16(ua.s, b0, acc, 0, 0, 0);
            acc = __builtin_amdgcn_mfma_f32_16x16x32_bf16(ub.s, b1, acc, 0, 0, 0);
            if (!tail) {
                #pragma unroll
                for (int r = 0; r < 4; ++r) {
                    const float l = acc[r];
                    mm[dt] = fmaxf(mm[dt], l * flip[dt]);
                    sum2[dt] += sigm(l);
                }
            } else {
                #pragma unroll
                for (int r = 0; r < 4; ++r) {
                    const bool v = (jt * 16 + quad * 4 + r) < cnt;
                    const float lx = v ? acc[r] : -3.0e38f;            // sigm -> 0
                    const float pf = v ? acc[r] * flip[dt] : -3.0e38f; // never wins max
                    mm[dt] = fmaxf(mm[dt], pf);
                    sum2[dt] += sigm(lx);
                }
            }
        }
    }

    // per-wave reduce over quad, write partials, single barrier, combine
    #pragma unroll
    for (int dt = 0; dt < 8; ++dt) {
        float s = sum2[dt], M = mm[dt];
        s += __shfl_xor(s, 16, 64);  s += __shfl_xor(s, 32, 64);
        M  = fmaxf(M,  __shfl_xor(M, 16, 64));  M  = fmaxf(M,  __shfl_xor(M, 32, 64));
        if (quad == 0) {
            sh_rsum[w * DD + dt * 16 + m16] = s;
            sh_rmax[w * DD + dt * 16 + m16] = M;
        }
    }
    __syncthreads();   // barrier 3: partials ready

    if (t < DD) {
        const int d = t;
        const float S = sh_rsum[d] + sh_rsum[DD + d] + sh_rsum[2 * DD + d] + sh_rsum[3 * DD + d];
        const float M = fmaxf(fmaxf(sh_rmax[d], sh_rmax[DD + d]),
                              fmaxf(sh_rmax[2 * DD + d], sh_rmax[3 * DD + d]));
        const float hd = h_g[bi * DD + d];
        const float fl = (hd >= 0.f) ? 1.f : -1.f;
        float mean = 0.f, amax = 0.f;
        if (cnt > 0) {
            mean = hd * S * __fdividef(1.f, (float)cnt);
            amax = hd * sigm(fl * M);   // fl=+1: max l; fl=-1: min l
        }
        aggf[bi * 256 + d]       = mean;
        aggf[bi * 256 + 128 + d] = amax;
    }
}

// ---------------- Kernel 2: batched update MLP + LayerNorm ----------------
// 16 rows/block, 128 blocks. B-matrices pre-packed bf16 by gate (u1t, u2t)
// in frag-major [k>>3][d][k&7] layout -> fully coalesced B loads here.
__global__ __launch_bounds__(256, 2)
void ecgc_upd(const float* __restrict__ h_g,
              const float* __restrict__ aggf,
              const unsigned short* __restrict__ u1t,
              const unsigned short* __restrict__ u2t,
              const float* __restrict__ b3_g,
              const float* __restrict__ b4_g,
              const float* __restrict__ gam_g,
              const float* __restrict__ bet_g,
              float*       __restrict__ out_g)
{
    const int bi0  = blockIdx.x * 16;
    const int t    = threadIdx.x;
    const int lane = t & 63;
    const int w    = t >> 6;
    const int m16  = lane & 15;
    const int quad = lane >> 4;

    __shared__ __align__(16) unsigned short shA[16 * APAD];
    __shared__ __align__(16) unsigned short rbuf[16 * RPAD];
    __shared__ float sh_s[4 * 16], sh_s2[4 * 16], sh_mu[16], sh_rs[16];

    {
        const int row = t >> 4, q = t & 15;
        const float* hrow = h_g  + (size_t)(bi0 + row) * DD;
        const float* wrow = aggf + (size_t)(bi0 + row) * 256;
        unsigned short tmp[24];
        #pragma unroll
        for (int c = 0; c < 24; ++c) {
            const int col = q * 24 + c;
            float v;
            if (col < 128)      v = hrow[col];
            else if (col < 256) v = wrow[col - 128];
            else                v = wrow[col - 256 + 128];
            tmp[c] = f2bf(v);
        }
        #pragma unroll
        for (int s8 = 0; s8 < 3; ++s8)
            *(short8*)&shA[row * APAD + q * 24 + s8 * 8] = *(const short8*)&tmp[s8 * 8];
    }
    __syncthreads();

    const int dstripe = w * 32;

    f32x4 acc[2];
    #pragma unroll
    for (int dt = 0; dt < 2; ++dt) {
        const float bb = b3_g[dstripe + dt * 16 + m16];
        acc[dt] = (f32x4){bb, bb, bb, bb};
    }
    for (int kk = 0; kk < 12; ++kk) {
        const short8 a0 = *(const short8*)&shA[m16 * APAD + kk * 32 + quad * 8];
        #pragma unroll
        for (int dt = 0; dt < 2; ++dt) {
            const int d = dstripe + dt * 16 + m16;
            const short8 b = *(const short8*)&u1t[(size_t)((kk * 4 + quad) * DD + d) * 8];
            acc[dt] = __builtin_amdgcn_mfma_f32_16x16x32_bf16(a0, b, acc[dt], 0, 0, 0);
        }
    }

    #pragma unroll
    for (int dt = 0; dt < 2; ++dt) {
        const int d = dstripe + dt * 16 + m16;
        #pragma unroll
        for (int r = 0; r < 4; ++r) {
            const int ro = quad * 4 + r;
            rbuf[ro * RPAD + d] = f2bf(fmaxf(acc[dt][r], 0.f));
        }
    }
    __syncthreads();

    f32x4 acc2[2];
    #pragma unroll
    for (int dt = 0; dt < 2; ++dt) {
        const float bb = b4_g[dstripe + dt * 16 + m16];
        acc2[dt] = (f32x4){bb, bb, bb, bb};
    }
    for (int kk = 0; kk < 4; ++kk) {
        const short8 a0 = *(const short8*)&rbuf[m16 * RPAD + kk * 32 + quad * 8];
        #pragma unroll
        for (int dt = 0; dt < 2; ++dt) {
            const int d = dstripe + dt * 16 + m16;
            const short8 b = *(const short8*)&u2t[(size_t)((kk * 4 + quad) * DD + d) * 8];
            acc2[dt] = __builtin_amdgcn_mfma_f32_16x16x32_bf16(a0, b, acc2[dt], 0, 0, 0);
        }
    }

    float xv[2][4];
    #pragma unroll
    for (int dt = 0; dt < 2; ++dt) {
        const int d = dstripe + dt * 16 + m16;
        #pragma unroll
        for (int r = 0; r < 4; ++r) {
            const int ro = quad * 4 + r;
            xv[dt][r] = h_g[(size_t)(bi0 + ro) * DD + d] + acc2[dt][r];
        }
    }

    #pragma unroll
    for (int r = 0; r < 4; ++r) {
        float s  = xv[0][r] + xv[1][r];
        float s2 = xv[0][r] * xv[0][r] + xv[1][r] * xv[1][r];
        #pragma unroll
        for (int off = 1; off < 16; off <<= 1) {
            s  += __shfl_xor(s,  off, 64);
            s2 += __shfl_xor(s2, off, 64);
        }
        if (m16 == 0) {
            const int ro = quad * 4 + r;
            sh_s[w * 16 + ro]  = s;
            sh_s2[w * 16 + ro] = s2;
        }
    }
    __syncthreads();
    if (t < 16) {
        const float S  = sh_s[t]  + sh_s[16 + t]  + sh_s[32 + t]  + sh_s[48 + t];
        const float S2 = sh_s2[t] + sh_s2[16 + t] + sh_s2[32 + t] + sh_s2[48 + t];
        const float mu  = S * (1.f / 128.f);
        const float var = S2 * (1.f / 128.f) - mu * mu;
        sh_mu[t] = mu;
        sh_rs[t] = rsqrtf(var + 1e-5f);
    }
    __syncthreads();

    #pragma unroll
    for (int dt = 0; dt < 2; ++dt) {
        const int d = dstripe + dt * 16 + m16;
        const float ga = gam_g[d], be = bet_g[d];
        #pragma unroll
        for (int r = 0; r < 4; ++r) {
            const int ro = quad * 4 + r;
            out_g[(size_t)(bi0 + ro) * DD + d] =
                (xv[dt][r] - sh_mu[ro]) * sh_rs[ro] * ga + be;
        }
    }
}

extern "C" void kernel_launch(void* const* d_in, const int* in_sizes, int n_in,
                              void* d_out, int out_size, void* d_ws, size_t ws_size,
                              hipStream_t stream) {
    float* aggf = (float*)d_ws;                                    // 2 MB
    unsigned short* u1t = (unsigned short*)((char*)d_ws + (size_t)2048 * 256 * 4);
    unsigned short* u2t = u1t + 384 * DD;                          // +96 KB
    ecgc_gate<<<8 * NN, 256, 0, stream>>>(
        (const float*)d_in[0],   // h
        (const float*)d_in[1],   // edge_feats
        (const int*)d_in[2],     // adj_mask
        (const float*)d_in[3],   // W1
        (const float*)d_in[4],   // b1
        (const float*)d_in[5],   // W2
        (const float*)d_in[6],   // b2
        (const float*)d_in[7],   // U1
        (const float*)d_in[9],   // U2
        aggf, u1t, u2t);
    ecgc_upd<<<(8 * NN) / 16, 256, 0, stream>>>(
        (const float*)d_in[0],   // h
        aggf, u1t, u2t,
        (const float*)d_in[8],   // b3
        (const float*)d_in[10],  // b4
        (const float*)d_in[11],  // gamma
        (const float*)d_in[12],  // beta
        (float*)d_out);
}

// Round 4
// 118.241 us; speedup vs baseline: 2.5861x; 2.5861x over previous
//
#include <hip/hip_runtime.h>
#include <hip/hip_bf16.h>
#include <math.h>

#define NN 256
#define DD 128
#define EE 64
#define APAD 392   // kernel2 A row stride (ushorts)
#define RPAD 136   // kernel2 rbuf row stride (ushorts)

typedef __attribute__((ext_vector_type(8))) short short8;
typedef __attribute__((ext_vector_type(4))) float f32x4;

static __device__ __forceinline__ unsigned short f2bf(float f) {
    __hip_bfloat16 b = __float2bfloat16(f);
    return *reinterpret_cast<unsigned short*>(&b);
}

static __device__ __forceinline__ float sigm(float l) {
    return __fdividef(1.f, 1.f + __expf(-l));
}

// bf16 B-fragment for mfma_16x16x32 from row-major f32 B[K][128] in global.
static __device__ __forceinline__ short8 ldb(const float* __restrict__ B, int kbase, int d) {
    unsigned short tmp[8];
    #pragma unroll
    for (int j = 0; j < 8; ++j) tmp[j] = f2bf(B[(kbase + j) * DD + d]);
    return *(const short8*)tmp;
}

// ---------------- Kernel 1: gate + masked aggregation (+ u1t/u2t pack) -------
// R15 == R14 resubmit (round-3 bench died to container acquire failure, not a
// kernel fault; barrier-uniformity + ring-race + LDS-bounds re-audited).
// Structure: R12 (verified 116us) + 4-slot P ring so the hot loop barriers
// every TWO tiles instead of every tile.  Cooperative build: all 256 threads
// build P[16j][64e] once per tile (16 fma + 2 cvt + 1 b64 write), waves read
// A-fragments via swizzled ds_read_b128.  Per-lane live set stays small
// (R13 post-mortem: 8-dt j-ownership spilled 570 MB scratch — NEVER grow it).
// Slot-race analysis for the 2-tile barrier window {2k,2k+1}: reads hit
// slots (2k)&3,(2k+1)&3; builds write (2k+2)&3,(2k+3)&3 — disjoint.
__global__ __launch_bounds__(256, 4)
void ecgc_gate(const float* __restrict__ h_g,
               const float* __restrict__ ef_g,
               const int*   __restrict__ mask_g,
               const float* __restrict__ W1_g,
               const float* __restrict__ b1_g,
               const float* __restrict__ W2_g,
               const float* __restrict__ b2_g,
               const float* __restrict__ U1_g,
               const float* __restrict__ U2_g,
               float*          __restrict__ aggf,
               unsigned short* __restrict__ u1t,
               unsigned short* __restrict__ u2t)
{
    const int bi   = blockIdx.x;
    const int t    = threadIdx.x;
    const int lane = t & 63;
    const int w    = t >> 6;
    const int m16  = lane & 15;
    const int quad = lane >> 4;
    // build-role indices: thread owns (j = bj, e = beb..beb+3)
    const int bj   = t & 15;
    const int beb  = (t >> 4) << 2;

    __shared__ __align__(16) float sh_ef4[NN * 4];   // 4 KB
    __shared__ __align__(16) float sh_q4[EE * 4];    // 1 KB {base,w10,w11,w12}
    __shared__ float sh_basep[4 * EE];               // 1 KB
    __shared__ float sh_w1e[3 * EE];
    __shared__ int   sh_jlist[NN], sh_wcnt[4], sh_cnt;
    __shared__ __align__(16) unsigned short sh_P[4][16 * EE];  // 8 KB ring, swizzled

    // ---- u1t/u2t bf16 pack slice: 65536 elems over 2048 blocks ----
    // frag-major [k>>3][d][k&7]: kernel2's B loads are 256-B coalesced runs.
    if (t < 32) {
        const int flat = bi * 32 + t;
        if (flat < 384 * DD) {
            const int d = flat / 384, k = flat - d * 384;
            u1t[((k >> 3) * DD + d) * 8 + (k & 7)] = f2bf(U1_g[k * DD + d]);
        } else {
            const int f2i = flat - 384 * DD;
            const int d = f2i >> 7, k = f2i & 127;
            u2t[((k >> 3) * DD + d) * 8 + (k & 7)] = f2bf(U2_g[k * DD + d]);
        }
    }

    // ---- stage ----
    {
        const float* efr = ef_g + (size_t)bi * NN * 3;
        sh_ef4[t * 4 + 0] = efr[t * 3 + 0];
        sh_ef4[t * 4 + 1] = efr[t * 3 + 1];
        sh_ef4[t * 4 + 2] = efr[t * 3 + 2];
        sh_ef4[t * 4 + 3] = 0.f;
    }
    if (t < 192) sh_w1e[t] = W1_g[(DD + (t >> 6)) * EE + (t & 63)];

    const int mk = (mask_g[bi * NN + t] != 0) ? 1 : 0;
    const unsigned long long bal = __ballot(mk);
    if (lane == 0) sh_wcnt[w] = __popcll(bal);
    const int pre = __popcll(bal & ((1ull << lane) - 1ull));

    // basep: thread (e = t&63) partial over d-range [w*32, w*32+32)
    {
        const int e = t & 63;
        float acc = 0.f;
        #pragma unroll 8
        for (int d = w * 32; d < w * 32 + 32; ++d)
            acc = fmaf(h_g[bi * DD + d], W1_g[d * EE + e], acc);
        sh_basep[w * EE + e] = acc;
    }

    // W2 B-fragments; b2 for C-init; h_d and sign-flip per d-tile
    const int dstripe = w * 32;
    short8 bfrag[2][2];
    float  nb2[2], hd2[2], flip[2];
    #pragma unroll
    for (int dt = 0; dt < 2; ++dt) {
        const int d = dstripe + 16 * dt + m16;
        nb2[dt] = b2_g[d];
        hd2[dt] = h_g[bi * DD + d];
        flip[dt] = (hd2[dt] >= 0.f) ? 1.f : -1.f;
        #pragma unroll
        for (int kh = 0; kh < 2; ++kh)
            bfrag[dt][kh] = ldb(W2_g, kh * 32 + quad * 8, d);
    }
    __syncthreads();   // barrier 1: wcnt/basep/w1e ready

    {
        int wbase = 0;
        for (int ww = 0; ww < w; ++ww) wbase += sh_wcnt[ww];
        if (mk) sh_jlist[wbase + pre] = t;
        if (t == 0) sh_cnt = sh_wcnt[0] + sh_wcnt[1] + sh_wcnt[2] + sh_wcnt[3];
    }
    if (t < EE) {
        const float base = b1_g[t] + sh_basep[t] + sh_basep[EE + t] +
                           sh_basep[2 * EE + t] + sh_basep[3 * EE + t];
        sh_q4[t * 4 + 0] = base;
        sh_q4[t * 4 + 1] = sh_w1e[t];
        sh_q4[t * 4 + 2] = sh_w1e[EE + t];
        sh_q4[t * 4 + 3] = sh_w1e[2 * EE + t];
    }
    __syncthreads();   // barrier 2: jlist/q4 ready

    // build constants: this thread's 4 {base,w1e} rows (fixed e -> stays in reg)
    f32x4 qreg[4];
    #pragma unroll
    for (int i = 0; i < 4; ++i) qreg[i] = *(const f32x4*)&sh_q4[(beb + i) * 4];

    const int cnt = sh_cnt;
    const int njt = (cnt + 15) >> 4;

    // swizzled LDS addressing (byte ^= ((row&7)<<4), bijective, b128-aligned)
    const int   sw_r = (m16 & 7) << 4;
    const char* prow = (const char*)&sh_P[0][m16 * EE];
    const int   offA = (quad * 16) ^ sw_r;        // kh=0: e 0..31
    const int   offB = (64 + quad * 16) ^ sw_r;   // kh=1: e 32..63
    char* pwr;
    {
        const int cb = 2 * beb;   // byte col of this thread's 4 e-values
        const int cs = (cb & 8) | ((((cb >> 4) ^ (bj & 7)) & 7) << 4);
        pwr = (char*)&sh_P[0][bj * EE] + cs;
    }

    float sum2[2] = {0.f, 0.f};
    float mm[2]   = {-3.0e38f, -3.0e38f};   // max over j of flip*logit

    auto buildP = [&](int jtile, int bufbyte) {
        const int row = jtile * 16 + bj;
        int jl = sh_jlist[row];
        jl = (row < cnt) ? jl : 0;              // clamp stale tail values
        const float4 efv = *(const float4*)&sh_ef4[jl * 4];
        float v[4];
        #pragma unroll
        for (int i = 0; i < 4; ++i)
            v[i] = fmaxf(fmaf(efv.z, qreg[i][3], fmaf(efv.y, qreg[i][2],
                         fmaf(efv.x, qreg[i][1], qreg[i][0]))), 0.f);
        union { __hip_bfloat162 h2; unsigned int u; } a0, a1;
        a0.h2 = __float22bfloat162_rn(make_float2(v[0], v[1]));
        a1.h2 = __float22bfloat162_rn(make_float2(v[2], v[3]));
        *reinterpret_cast<uint2*>(pwr + bufbyte) = make_uint2(a0.u, a1.u);
    };

    if (njt > 0) buildP(0, 0);
    if (njt > 1) buildP(1, 2048);
    __syncthreads();   // barrier 3: tiles 0,1 built

    for (int jt = 0; jt < njt; ++jt) {
        const int bo = (jt & 3) << 11;          // 2048-byte slot stride, 4-ring
        const short8 ua = *(const short8*)(prow + bo + offA);
        const short8 ub = *(const short8*)(prow + bo + offB);

        // build tile jt+2 into its ring slot (overlaps MFMA+epilogue)
        if (jt + 2 < njt) buildP(jt + 2, ((jt + 2) & 3) << 11);

        const bool tail = (jt == njt - 1) && (cnt & 15);
        #pragma unroll
        for (int dt = 0; dt < 2; ++dt) {
            f32x4 acc = {nb2[dt], nb2[dt], nb2[dt], nb2[dt]};
            acc = __builtin_amdgcn_mfma_f32_16x16x32_bf16(ua, bfrag[dt][0], acc, 0, 0, 0);
            acc = __builtin_amdgcn_mfma_f32_16x16x32_bf16(ub, bfrag[dt][1], acc, 0, 0, 0);
            if (!tail) {
                #pragma unroll
                for (int r = 0; r < 4; ++r) {
                    const float l = acc[r];
                    mm[dt] = fmaxf(mm[dt], l * flip[dt]);
                    sum2[dt] += sigm(l);
                }
            } else {
                #pragma unroll
                for (int r = 0; r < 4; ++r) {
                    const bool v = (jt * 16 + quad * 4 + r) < cnt;
                    const float lx = v ? acc[r] : -3.0e38f;            // sigm -> 0
                    const float pf = v ? acc[r] * flip[dt] : -3.0e38f; // never wins max
                    mm[dt] = fmaxf(mm[dt], pf);
                    sum2[dt] += sigm(lx);
                }
            }
        }
        if (jt & 1) __syncthreads();   // barrier every 2 tiles (window analysis above)
    }

    // cross-quad reduce; sigmoid applied once on the extreme logit (monotone)
    #pragma unroll
    for (int dt = 0; dt < 2; ++dt) {
        float s = sum2[dt], M = mm[dt];
        s += __shfl_xor(s, 16, 64);  s += __shfl_xor(s, 32, 64);
        M  = fmaxf(M,  __shfl_xor(M, 16, 64));  M  = fmaxf(M,  __shfl_xor(M, 32, 64));
        if (quad == 0) {
            const int d = dstripe + 16 * dt + m16;
            const float hd = hd2[dt];
            float mean = 0.f, amax = 0.f;
            if (cnt > 0) {
                mean = hd * s * __fdividef(1.f, (float)cnt);
                amax = hd * sigm(flip[dt] * M);   // flip=+1: max l; flip=-1: min l
            }
            aggf[bi * 256 + d]       = mean;
            aggf[bi * 256 + 128 + d] = amax;
        }
    }
}

// ---------------- Kernel 2: batched update MLP + LayerNorm ----------------
// R15: 8 rows/block, 256 blocks (was 16/128): doubles CU coverage of this
// latency-bound kernel.  MFMA tile rows 8..15 duplicate rows 0..7 (same
// data -> same results); output writes guarded to ro<8.  MFMA count doubles
// but MfmaUtil was ~1% — occupancy, not throughput, is the limit here.
// B-matrices pre-packed bf16 by gate (u1t, u2t) in frag-major
// [k>>3][d][k&7] layout -> fully coalesced B loads.
__global__ __launch_bounds__(256, 2)
void ecgc_upd(const float* __restrict__ h_g,
              const float* __restrict__ aggf,
              const unsigned short* __restrict__ u1t,
              const unsigned short* __restrict__ u2t,
              const float* __restrict__ b3_g,
              const float* __restrict__ b4_g,
              const float* __restrict__ gam_g,
              const float* __restrict__ bet_g,
              float*       __restrict__ out_g)
{
    const int bi0  = blockIdx.x * 8;
    const int t    = threadIdx.x;
    const int lane = t & 63;
    const int w    = t >> 6;
    const int m16  = lane & 15;
    const int quad = lane >> 4;

    __shared__ __align__(16) unsigned short shA[16 * APAD];
    __shared__ __align__(16) unsigned short rbuf[16 * RPAD];
    __shared__ float sh_s[4 * 16], sh_s2[4 * 16], sh_mu[16], sh_rs[16];

    {
        const int row = t >> 4, q = t & 15;
        const int pr  = bi0 + (row & 7);           // rows 8..15 duplicate 0..7
        const float* hrow = h_g  + (size_t)pr * DD;
        const float* wrow = aggf + (size_t)pr * 256;
        unsigned short tmp[24];
        #pragma unroll
        for (int c = 0; c < 24; ++c) {
            const int col = q * 24 + c;
            float v;
            if (col < 128)      v = hrow[col];
            else if (col < 256) v = wrow[col - 128];
            else                v = wrow[col - 256 + 128];
            tmp[c] = f2bf(v);
        }
        #pragma unroll
        for (int s8 = 0; s8 < 3; ++s8)
            *(short8*)&shA[row * APAD + q * 24 + s8 * 8] = *(const short8*)&tmp[s8 * 8];
    }
    __syncthreads();

    const int dstripe = w * 32;

    f32x4 acc[2];
    #pragma unroll
    for (int dt = 0; dt < 2; ++dt) {
        const float bb = b3_g[dstripe + dt * 16 + m16];
        acc[dt] = (f32x4){bb, bb, bb, bb};
    }
    for (int kk = 0; kk < 12; ++kk) {
        const short8 a0 = *(const short8*)&shA[m16 * APAD + kk * 32 + quad * 8];
        #pragma unroll
        for (int dt = 0; dt < 2; ++dt) {
            const int d = dstripe + dt * 16 + m16;
            const short8 b = *(const short8*)&u1t[(size_t)((kk * 4 + quad) * DD + d) * 8];
            acc[dt] = __builtin_amdgcn_mfma_f32_16x16x32_bf16(a0, b, acc[dt], 0, 0, 0);
        }
    }

    #pragma unroll
    for (int dt = 0; dt < 2; ++dt) {
        const int d = dstripe + dt * 16 + m16;
        #pragma unroll
        for (int r = 0; r < 4; ++r) {
            const int ro = quad * 4 + r;
            rbuf[ro * RPAD + d] = f2bf(fmaxf(acc[dt][r], 0.f));
        }
    }
    __syncthreads();

    f32x4 acc2[2];
    #pragma unroll
    for (int dt = 0; dt < 2; ++dt) {
        const float bb = b4_g[dstripe + dt * 16 + m16];
        acc2[dt] = (f32x4){bb, bb, bb, bb};
    }
    for (int kk = 0; kk < 4; ++kk) {
        const short8 a0 = *(const short8*)&rbuf[m16 * RPAD + kk * 32 + quad * 8];
        #pragma unroll
        for (int dt = 0; dt < 2; ++dt) {
            const int d = dstripe + dt * 16 + m16;
            const short8 b = *(const short8*)&u2t[(size_t)((kk * 4 + quad) * DD + d) * 8];
            acc2[dt] = __builtin_amdgcn_mfma_f32_16x16x32_bf16(a0, b, acc2[dt], 0, 0, 0);
        }
    }

    float xv[2][4];
    #pragma unroll
    for (int dt = 0; dt < 2; ++dt) {
        const int d = dstripe + dt * 16 + m16;
        #pragma unroll
        for (int r = 0; r < 4; ++r) {
            const int ro = quad * 4 + r;
            xv[dt][r] = h_g[(size_t)(bi0 + (ro & 7)) * DD + d] + acc2[dt][r];
        }
    }

    #pragma unroll
    for (int r = 0; r < 4; ++r) {
        float s  = xv[0][r] + xv[1][r];
        float s2 = xv[0][r] * xv[0][r] + xv[1][r] * xv[1][r];
        #pragma unroll
        for (int off = 1; off < 16; off <<= 1) {
            s  += __shfl_xor(s,  off, 64);
            s2 += __shfl_xor(s2, off, 64);
        }
        if (m16 == 0) {
            const int ro = quad * 4 + r;
            sh_s[w * 16 + ro]  = s;
            sh_s2[w * 16 + ro] = s2;
        }
    }
    __syncthreads();
    if (t < 16) {
        const float S  = sh_s[t]  + sh_s[16 + t]  + sh_s[32 + t]  + sh_s[48 + t];
        const float S2 = sh_s2[t] + sh_s2[16 + t] + sh_s2[32 + t] + sh_s2[48 + t];
        const float mu  = S * (1.f / 128.f);
        const float var = S2 * (1.f / 128.f) - mu * mu;
        sh_mu[t] = mu;
        sh_rs[t] = rsqrtf(var + 1e-5f);
    }
    __syncthreads();

    #pragma unroll
    for (int dt = 0; dt < 2; ++dt) {
        const int d = dstripe + dt * 16 + m16;
        const float ga = gam_g[d], be = bet_g[d];
        #pragma unroll
        for (int r = 0; r < 4; ++r) {
            const int ro = quad * 4 + r;
            if (ro < 8)
                out_g[(size_t)(bi0 + ro) * DD + d] =
                    (xv[dt][r] - sh_mu[ro]) * sh_rs[ro] * ga + be;
        }
    }
}

extern "C" void kernel_launch(void* const* d_in, const int* in_sizes, int n_in,
                              void* d_out, int out_size, void* d_ws, size_t ws_size,
                              hipStream_t stream) {
    float* aggf = (float*)d_ws;                                    // 2 MB
    unsigned short* u1t = (unsigned short*)((char*)d_ws + (size_t)2048 * 256 * 4);
    unsigned short* u2t = u1t + 384 * DD;                          // +96 KB
    ecgc_gate<<<8 * NN, 256, 0, stream>>>(
        (const float*)d_in[0],   // h
        (const float*)d_in[1],   // edge_feats
        (const int*)d_in[2],     // adj_mask
        (const float*)d_in[3],   // W1
        (const float*)d_in[4],   // b1
        (const float*)d_in[5],   // W2
        (const float*)d_in[6],   // b2
        (const float*)d_in[7],   // U1
        (const float*)d_in[9],   // U2
        aggf, u1t, u2t);
    ecgc_upd<<<NN, 256, 0, stream>>>(
        (const float*)d_in[0],   // h
        aggf, u1t, u2t,
        (const float*)d_in[8],   // b3
        (const float*)d_in[10],  // b4
        (const float*)d_in[11],  // gamma
        (const float*)d_in[12],  // beta
        (float*)d_out);
}